// Round 4
// baseline (13728.722 us; speedup 1.0000x reference)
//
#include <hip/hip_runtime.h>
#include <cstdint>
#include <cstddef>

#define LSEQ 8192
#define NT   34
#define NP   36
#define SCH  64
#define CCH  128
#define F_L2E 1.4426950408889634f
#define F_LN2 0.6931471805599453f

#if __has_builtin(__builtin_amdgcn_sdot4)
#define DOT4(a,b,c) __builtin_amdgcn_sdot4((a),(b),(c),false)
#else
__device__ __forceinline__ int dot4_fb(int a,int b,int c){
  c += (int)(signed char)(a & 0xff)        * (int)(signed char)(b & 0xff);
  c += (int)(signed char)((a>>8) & 0xff)   * (int)(signed char)((b>>8) & 0xff);
  c += (int)(signed char)((a>>16) & 0xff)  * (int)(signed char)((b>>16) & 0xff);
  c += (a>>24) * (b>>24);
  return c;
}
#define DOT4(a,b,c) dot4_fb((a),(b),(c))
#endif

__device__ __forceinline__ float ex2(float x){ return exp2f(x); }
__device__ __forceinline__ float lg2(float x){ return __log2f(x); }

__device__ __forceinline__ float sigf(float x){
  return __fdividef(1.f, 1.f + ex2(-F_L2E * x));
}
__device__ __forceinline__ float tanhf_fast(float x){
  return 1.f - __fdividef(2.f, ex2(2.f * F_L2E * x) + 1.f);
}

// barrier without the vmcnt(0) drain: LDS-only fence + s_barrier.
__device__ __forceinline__ void barrier_lds(){
  asm volatile("s_waitcnt lgkmcnt(0)\n\ts_barrier" ::: "memory");
}

// ---------------------------------------------------------------------------
// Kernel 1: quantize Whh (both dirs) to int8 per-row. Wq: [dir][row r][64 dw]
// facP permuted: [dir][u*4+g]  (r = g*256+u)
// ---------------------------------------------------------------------------
__global__ void k_quant(const float* __restrict__ Whh_f,
                        const float* __restrict__ Whh_b,
                        int* __restrict__ Wq, float* __restrict__ facP){
  int bid = blockIdx.x;
  int dir = bid >> 10;
  int r   = bid & 1023;
  int i   = threadIdx.x;           // 0..63
  const float* W = (dir ? Whh_b : Whh_f) + r * 256 + i * 4;
  float w0 = W[0], w1 = W[1], w2 = W[2], w3 = W[3];
  float m = fmaxf(fmaxf(fabsf(w0), fabsf(w1)), fmaxf(fabsf(w2), fabsf(w3)));
  for (int s = 32; s; s >>= 1) m = fmaxf(m, __shfl_xor(m, s));
  float scale = (m > 0.f) ? m / 127.f : 1.f;
  float inv = __fdividef(1.f, scale);
  int q0 = (int)rintf(w0 * inv), q1 = (int)rintf(w1 * inv);
  int q2 = (int)rintf(w2 * inv), q3 = (int)rintf(w3 * inv);
  q0 = max(-127, min(127, q0)); q1 = max(-127, min(127, q1));
  q2 = max(-127, min(127, q2)); q3 = max(-127, min(127, q3));
  int p = (q0 & 255) | ((q1 & 255) << 8) | ((q2 & 255) << 16) | ((q3 & 255) << 24);
  Wq[(dir << 16) + (r << 6) + i] = p;
  if (i == 0) {
    int g = r >> 8, u = r & 255;
    facP[(dir << 10) + u * 4 + g] = scale * (1.f / 127.f);
  }
}

// ---------------------------------------------------------------------------
// Kernel 2: G'[t][u*4+g] = b[g*256+u] + sum_e x[t][e] * Wih[g*256+u][e]
// Permuted gate-interleaved layout, coalesced float4 stores.
// ---------------------------------------------------------------------------
__global__ void k_gproj(const int* __restrict__ words,
                        const float* __restrict__ embed,
                        const float* __restrict__ Wih_f, const float* __restrict__ b_f,
                        const float* __restrict__ Wih_b, const float* __restrict__ b_b,
                        float* __restrict__ G_f, float* __restrict__ G_b){
  int dir = blockIdx.y;
  const float* Wih = dir ? Wih_b : Wih_f;
  const float* bb  = dir ? b_b  : b_f;
  float* G = dir ? G_b : G_f;
  int t0 = blockIdx.x * 16;
  int uu = threadIdx.x;            // unit 0..255
  __shared__ __align__(16) float X[16 * 256];
  for (int idx = threadIdx.x; idx < 16 * 256; idx += 256) {
    int tt = idx >> 8, e = idx & 255;
    X[idx] = embed[(size_t)words[t0 + tt] * 256 + e];
  }
  __syncthreads();
  const float4* X4 = (const float4*)X;
  const float4* Wr0 = (const float4*)(Wih + (size_t)(uu)       * 256);
  const float4* Wr1 = (const float4*)(Wih + (size_t)(uu + 256) * 256);
  const float4* Wr2 = (const float4*)(Wih + (size_t)(uu + 512) * 256);
  const float4* Wr3 = (const float4*)(Wih + (size_t)(uu + 768) * 256);
  float b0 = bb[uu], b1 = bb[uu + 256], b2 = bb[uu + 512], b3 = bb[uu + 768];
  for (int pass = 0; pass < 2; pass++) {
    float4 acc[8];
#pragma unroll
    for (int tt = 0; tt < 8; tt++) acc[tt] = make_float4(b0, b1, b2, b3);
    for (int eb = 0; eb < 64; eb++) {
      float4 w0 = Wr0[eb], w1 = Wr1[eb], w2 = Wr2[eb], w3 = Wr3[eb];
#pragma unroll
      for (int tt = 0; tt < 8; tt++) {
        float4 x = X4[(pass * 8 + tt) * 64 + eb];
        acc[tt].x += w0.x * x.x + w0.y * x.y + w0.z * x.z + w0.w * x.w;
        acc[tt].y += w1.x * x.x + w1.y * x.y + w1.z * x.z + w1.w * x.w;
        acc[tt].z += w2.x * x.x + w2.y * x.y + w2.z * x.z + w2.w * x.w;
        acc[tt].w += w3.x * x.x + w3.y * x.y + w3.z * x.z + w3.w * x.w;
      }
    }
#pragma unroll
    for (int tt = 0; tt < 8; tt++)
      *(float4*)(G + (size_t)(t0 + pass * 8 + tt) * 1024 + uu * 4) = acc[tt];
  }
}

// ---------------------------------------------------------------------------
// Kernel 3: LSTM recurrence, dot4 on 1024 threads (16 waves, 4/SIMD).
// Thread tid = w*64+l owns row r = g*256+u, u = w*16+(l>>2), g = l&3.
// Quad (lanes 4k..4k+3) owns the 4 gate rows of one unit -> pre-activation
// exchange is 4 intra-wave shuffles, gate math redundant per quad, NO
// second barrier. h int8 double-buffered in LDS; ONE lgkm barrier/step.
// G gate-interleaved: per-step load is G[time][tid] (coalesced dword).
// ---------------------------------------------------------------------------
__global__ __launch_bounds__(1024) void k_lstm4(const int* __restrict__ Wq,
                                                const float* __restrict__ facP,
                                                const float* __restrict__ G_f,
                                                const float* __restrict__ G_b,
                                                float* __restrict__ hf,
                                                float* __restrict__ hb){
  int dir = blockIdx.x;
  const int* Wqd = Wq + (dir << 16);
  const float* G = dir ? G_b : G_f;
  float* hout = dir ? hb : hf;
  int tid = threadIdx.x;
  int l = tid & 63;
  int g = l & 3;
  int u = tid >> 2;                 // unit 0..255  (== w*16 + (l>>2))
  int qbase = l & ~3;               // quad base lane

  __shared__ __align__(16) int h8[2 * 64];   // two 256-byte int8 h buffers

  // row weights: r = g*256 + u, 64 dwords in registers
  int r = g * 256 + u;
  const int4* wp = (const int4*)(Wqd + r * 64);
  int4 wreg[16];
#pragma unroll
  for (int kt = 0; kt < 16; kt++) wreg[kt] = wp[kt];

  float facv = facP[(dir << 10) + tid];
  int time0 = dir ? 8191 : 0;
  int time1 = dir ? 8190 : 1;
  float gcur = G[(size_t)time0 * 1024 + tid];
  float gnxt = G[(size_t)time1 * 1024 + tid];

  if (tid < 128) h8[tid] = 0;
  float c = 0.f;
  __syncthreads();

  for (int t = 0; t < 8192; t++) {
    // prefetch 2 steps ahead
    int tn2 = (t + 2 < 8192) ? t + 2 : 8191;
    int time2 = dir ? (8191 - tn2) : tn2;
    float gpre = G[(size_t)time2 * 1024 + tid];

    int p = t & 1;
    const int4* hb4 = (const int4*)(h8 + p * 64);
    int a0 = 0, a1 = 0, a2 = 0, a3 = 0;
#pragma unroll
    for (int kt = 0; kt < 16; kt++) {
      int4 hv = hb4[kt];                       // broadcast read
      a0 = DOT4(wreg[kt].x, hv.x, a0);
      a1 = DOT4(wreg[kt].y, hv.y, a1);
      a2 = DOT4(wreg[kt].z, hv.z, a2);
      a3 = DOT4(wreg[kt].w, hv.w, a3);
    }
    int acc = (a0 + a1) + (a2 + a3);
    float a = (float)acc * facv + gcur;

    // quad exchange: lane qbase+k computed gate k of unit u
    float ri = __shfl(a, qbase + 0);
    float rf = __shfl(a, qbase + 1);
    float rg = __shfl(a, qbase + 2);
    float ro = __shfl(a, qbase + 3);

    float is = sigf(ri), fs = sigf(rf);
    float gt = tanhf_fast(rg), os = sigf(ro);
    c = fs * c + is * gt;                      // identical across the quad
    float h = os * tanhf_fast(c);

    int time = dir ? (8191 - t) : t;
    if (g == 0) {
      hout[(size_t)time * 256 + u] = h;
      ((signed char*)h8)[(p ^ 1) * 256 + u] = (signed char)(int)rintf(h * 127.f);
    }
    gcur = gnxt; gnxt = gpre;
    barrier_lds();
  }
}

// ---------------------------------------------------------------------------
// Kernel 4: feats = [hf | hb] @ W_out.T + b_out.
// ---------------------------------------------------------------------------
__global__ void k_feats(const float* __restrict__ hf, const float* __restrict__ hb,
                        const float* __restrict__ W_out, const float* __restrict__ b_out,
                        float* __restrict__ feats){
  int t0 = blockIdx.x * 16;
  for (int oi = threadIdx.x; oi < 16 * NT; oi += 256) {
    int tt = oi / NT;
    int tag = oi - tt * NT;
    int t = t0 + tt;
    const float4* w4 = (const float4*)(W_out + (size_t)tag * 512);
    const float4* a4 = (const float4*)(hf + (size_t)t * 256);
    const float4* c4 = (const float4*)(hb + (size_t)t * 256);
    float acc = b_out[tag];
    for (int k = 0; k < 64; k++) {
      float4 w = w4[k]; float4 h = a4[k];
      acc += w.x * h.x + w.y * h.y + w.z * h.z + w.w * h.w;
    }
    for (int k = 0; k < 64; k++) {
      float4 w = w4[64 + k]; float4 h = c4[k];
      acc += w.x * h.x + w.y * h.y + w.z * h.z + w.w * h.w;
    }
    feats[(size_t)t * NT + tag] = acc;
  }
}

// ---------------------------------------------------------------------------
// CRF chunked associative scan, (lse,+) semiring, log2-domain (r2, unchanged).
// ---------------------------------------------------------------------------
__global__ __launch_bounds__(320) void k_crf_p1(const float* __restrict__ feats,
                                                const float* __restrict__ trans,
                                                float* __restrict__ Pg,
                                                float* __restrict__ rmaxG){
  int dir = blockIdx.x >> 7;
  int c   = blockIdx.x & (CCH - 1);
  int tid = threadIdx.x;
  int t0  = c * SCH;

  __shared__ __align__(16) float TRM[NT * NP];
  __shared__ float Fe[(SCH + 1) * NT];
  __shared__ __align__(16) float Pbuf[2][NT * NP];
  __shared__ float CM[NP];
  __shared__ float RMs[NT];

  for (int idx = tid; idx < NT * NT; idx += 320) {
    int j = idx / NT, k = idx - j * NT;
    float v = (dir == 0) ? trans[j * NT + k] : trans[k * NT + j];
    TRM[j * NP + k] = v * F_L2E;
  }
  for (int idx = tid; idx < (SCH + 1) * NT; idx += 320) {
    int s = idx / NT, j = idx - s * NT;
    int t = t0 + s; if (t > LSEQ - 1) t = LSEQ - 1;
    Fe[idx] = feats[(size_t)t * NT + j] * F_L2E;
  }
  for (int idx = tid; idx < NT * NP; idx += 320) {
    int k = idx / NP, i = idx - k * NP;
    Pbuf[0][idx] = (i < NT && i == k) ? 0.f : -1e30f;
  }
  if (tid < NP) CM[tid] = (tid < NT) ? 0.f : -1e30f;
  __syncthreads();
  if (tid < NT) {
    float m = -3e38f;
    for (int k = 0; k < NT; k++) m = fmaxf(m, TRM[tid * NP + k]);
    RMs[tid] = m;
  }
  __syncthreads();
  for (int idx = tid; idx < NT * NT; idx += 320) {
    int j = idx / NT, k = idx - j * NT;
    TRM[j * NP + k] -= RMs[j];
  }
  __syncthreads();

  int cur = 0;
  int j = tid / 9, g = tid - (tid / 9) * 9;
  bool act = (tid < 306);
  int i0 = 4 * g;

  for (int s = 0; s < SCH; s++) {
    int t = (dir == 0) ? (t0 + s) : (t0 + SCH - 1 - s);
    if (dir == 1 && t == LSEQ - 1) continue;   // identity factor at t=L-1
    const float* Pc = Pbuf[cur];
    float* Pn = Pbuf[cur ^ 1];
    if (act) {
      float cm0 = CM[i0], cm1 = CM[i0 + 1], cm2 = CM[i0 + 2], cm3 = CM[i0 + 3];
      float s0 = 0, s1 = 0, s2 = 0, s3 = 0;
      const float* trp = TRM + j * NP;
      const float* fep = Fe + (t + 1 - t0) * NT;
#pragma unroll
      for (int k = 0; k < NT; k++) {
        float trv = trp[k];
        if (dir == 1) trv += fep[k];
        float4 p = *(const float4*)&Pc[k * NP + i0];
        s0 += ex2(trv + p.x - cm0);
        s1 += ex2(trv + p.y - cm1);
        s2 += ex2(trv + p.z - cm2);
        s3 += ex2(trv + p.w - cm3);
      }
      float base = RMs[j] + ((dir == 0) ? Fe[(t - t0) * NT + j] : 0.f);
      float4 o;
      o.x = base + cm0 + lg2(s0);
      o.y = base + cm1 + lg2(s1);
      o.z = (i0 + 2 < NT) ? (base + cm2 + lg2(s2)) : -1e30f;
      o.w = (i0 + 3 < NT) ? (base + cm3 + lg2(s3)) : -1e30f;
      *(float4*)&Pn[j * NP + i0] = o;
    }
    __syncthreads();
    if (tid < NP) {
      float m = -3e38f;
      const float* colp = Pn + tid;
      for (int k = 0; k < NT; k++) m = fmaxf(m, colp[k * NP]);
      CM[tid] = m;
    }
    cur ^= 1;
    __syncthreads();
  }

  const float* Pf = Pbuf[cur];
  size_t base = (size_t)((dir << 7) + c) * (NT * NP);
  for (int idx = tid; idx < NT * NP; idx += 320)
    Pg[base + idx] = Pf[idx];
  if (tid < NT) {
    float m = -3e38f;
    for (int i = 0; i < NT; i++) m = fmaxf(m, Pf[tid * NP + i]);
    rmaxG[((dir << 7) + c) * NT + tid] = m;
  }
}

__global__ void k_crf_p2(const float* __restrict__ trans,
                         const float* __restrict__ Pg,
                         const float* __restrict__ rmaxG,
                         float* __restrict__ vIn){
  int dir = blockIdx.x;
  int lane = threadIdx.x;           // 64, single wave
  bool a = (lane < NT);
  int j = a ? lane : 0;
  __shared__ float V[NP];

  float v;
  if (dir == 0) {
    v = (lane == 32) ? 0.f : -10000.f * F_L2E;
  } else {
    float m = -3e38f;
    for (int i = 0; i < NT; i++) m = fmaxf(m, trans[i * NT + j]);
    float s = 0.f;
    for (int i = 0; i < NT; i++) s += ex2((trans[i * NT + j] - m) * F_L2E);
    v = m * F_L2E + lg2(s);
  }
  if (lane < NP) V[lane] = -1e30f;
  barrier_lds();
  if (a) V[j] = v;
  barrier_lds();
  float vm = a ? v : -3e38f;
  for (int off = 32; off; off >>= 1) vm = fmaxf(vm, __shfl_xor(vm, off));

  if (a) {
    int c0 = (dir == 0) ? 0 : (CCH - 1);
    vIn[((size_t)(dir << 7) + c0) * NP + j] = v;
  }

  for (int it = 0; it < CCH - 1; it++) {
    int c = (dir == 0) ? it : (CCH - 1 - it);
    const float* row = Pg + ((size_t)(dir << 7) + c) * (NT * NP) + j * NP;
    float rm = rmaxG[((dir << 7) + c) * NT + j];
    float m = rm + vm;
    float s = 0.f;
#pragma unroll
    for (int k = 0; k < NP; k += 4) {
      float4 p = *(const float4*)&row[k];
      s += ex2(p.x + V[k]     - m);
      s += ex2(p.y + V[k + 1] - m);
      s += ex2(p.z + V[k + 2] - m);
      s += ex2(p.w + V[k + 3] - m);
    }
    float nv = m + lg2(s);
    if (a) V[j] = nv;
    barrier_lds();
    float x = a ? nv : -3e38f;
    for (int off = 32; off; off >>= 1) x = fmaxf(x, __shfl_xor(x, off));
    vm = x;
    int cn = (dir == 0) ? (c + 1) : (c - 1);
    if (a) vIn[((size_t)(dir << 7) + cn) * NP + j] = nv;
  }
}

__global__ void k_crf_p3(const float* __restrict__ feats,
                         const float* __restrict__ trans,
                         const float* __restrict__ vIn,
                         float* __restrict__ wsA,
                         float* __restrict__ wsB){
  int dir = blockIdx.x >> 7;
  int c   = blockIdx.x & (CCH - 1);
  int lane = threadIdx.x;           // 64, single wave
  int t0 = c * SCH;
  bool a = (lane < NT);
  int j = a ? lane : 0;
  __shared__ float A[NP];
  __shared__ float U[NP];

  float trr[NT];
  float rm = -3e38f;
#pragma unroll
  for (int k = 0; k < NT; k++) {
    float vv = (dir == 0) ? trans[j * NT + k] : trans[k * NT + j];
    trr[k] = vv * F_L2E;
    rm = fmaxf(rm, trr[k]);
  }
  if (lane < NP) { A[lane] = -1e30f; U[lane] = -1e30f; }
  float v0 = vIn[((size_t)(dir << 7) + c) * NP + j];
  barrier_lds();
  if (a) A[j] = v0;
  barrier_lds();
  float am = a ? v0 : -3e38f;
  for (int off = 32; off; off >>= 1) am = fmaxf(am, __shfl_xor(am, off));

  if (dir == 0) {
    float fe = feats[(size_t)t0 * NT + j] * F_L2E;
    for (int s = 0; s < SCH; s++) {
      int t = t0 + s;
      int tn = (t + 1 < LSEQ) ? t + 1 : LSEQ - 1;
      float fe_n = feats[(size_t)tn * NT + j] * F_L2E;
      float m = rm + am;
      float ss = 0.f;
#pragma unroll
      for (int k = 0; k < NT; k++) ss += ex2(trr[k] + A[k] - m);
      float out = m + lg2(ss) + fe;
      if (a) wsA[(size_t)t * NT + j] = out * F_LN2;
      if (a) A[j] = out;
      barrier_lds();
      float x = a ? out : -3e38f;
      for (int off = 32; off; off >>= 1) x = fmaxf(x, __shfl_xor(x, off));
      am = x;
      fe = fe_n;
    }
  } else {
    float b = v0;
    int tfirst = t0 + SCH; if (tfirst > LSEQ - 1) tfirst = LSEQ - 1;
    float fe = feats[(size_t)tfirst * NT + j] * F_L2E;
    for (int s = 0; s < SCH; s++) {
      int t = t0 + SCH - 1 - s;
      float fe_n = feats[(size_t)t * NT + j] * F_L2E;
      float out;
      if (t == LSEQ - 1) {
        out = b;
      } else {
        if (a) U[j] = b + fe;
        barrier_lds();
        float um = a ? U[j] : -3e38f;
        for (int off = 32; off; off >>= 1) um = fmaxf(um, __shfl_xor(um, off));
        float m = rm + um;
        float ss = 0.f;
#pragma unroll
        for (int k = 0; k < NT; k++) ss += ex2(trr[k] + U[k] - m);
        out = m + lg2(ss);
        barrier_lds();
      }
      if (a) wsB[(size_t)t * NT + j] = out * F_LN2;
      b = out;
      fe = fe_n;
    }
  }
}

// ---------------------------------------------------------------------------
__global__ void k_finish(const float* __restrict__ wsA, const float* __restrict__ wsB,
                         float* __restrict__ out){
  int t = blockIdx.x * 256 + threadIdx.x;
  float m = -3e38f; int bi = 0;
  for (int i = 0; i < NT; i++) {
    float sc = wsA[(size_t)t * NT + i] + wsB[(size_t)t * NT + i];
    out[(size_t)t * NT + i] = sc;
    if (sc > m) { m = sc; bi = i; }
  }
  out[(size_t)LSEQ * NT + t] = (float)bi;
}

// ---------------------------------------------------------------------------
extern "C" void kernel_launch(void* const* d_in, const int* in_sizes, int n_in,
                              void* d_out, int out_size, void* d_ws, size_t ws_size,
                              hipStream_t stream) {
  const int*   words  = (const int*)  d_in[0];
  const float* embed  = (const float*)d_in[1];
  const float* Wih_f  = (const float*)d_in[2];
  const float* Whh_f  = (const float*)d_in[3];
  const float* b_f    = (const float*)d_in[4];
  const float* Wih_b  = (const float*)d_in[5];
  const float* Whh_b  = (const float*)d_in[6];
  const float* b_b    = (const float*)d_in[7];
  const float* W_out  = (const float*)d_in[8];
  const float* b_out  = (const float*)d_in[9];
  const float* trans  = (const float*)d_in[10];
  float* out = (float*)d_out;

  float* wsf = (float*)d_ws;
  size_t off = 0;
  float* G_f   = wsf + off; off += (size_t)LSEQ * 1024;
  float* G_b   = wsf + off; off += (size_t)LSEQ * 1024;
  float* hf    = wsf + off; off += (size_t)LSEQ * 256;
  float* hb    = wsf + off; off += (size_t)LSEQ * 256;
  float* feats = wsf + off; off += (size_t)LSEQ * NT + 16;
  float* wsA   = wsf + off; off += (size_t)LSEQ * NT + 16;
  float* wsB   = wsf + off; off += (size_t)LSEQ * NT + 16;
  float* facP  = wsf + off; off += 2048;
  int*   Wq    = (int*)(wsf + off); off += 2 * 1024 * 64;
  // CRF scan scratch overlaps G_f (dead after k_lstm4)
  float* Pg    = G_f;
  float* rmaxG = G_f + 256 * (NT * NP);
  float* vIn   = rmaxG + 256 * NT + 32;

  k_quant<<<2048, 64, 0, stream>>>(Whh_f, Whh_b, Wq, facP);
  k_gproj<<<dim3(512, 2), 256, 0, stream>>>(words, embed, Wih_f, b_f, Wih_b, b_b, G_f, G_b);
  k_lstm4<<<2, 1024, 0, stream>>>(Wq, facP, G_f, G_b, hf, hb);
  k_feats<<<512, 256, 0, stream>>>(hf, hb, W_out, b_out, feats);
  k_crf_p1<<<256, 320, 0, stream>>>(feats, trans, Pg, rmaxG);
  k_crf_p2<<<2, 64, 0, stream>>>(trans, Pg, rmaxG, vIn);
  k_crf_p3<<<256, 64, 0, stream>>>(feats, trans, vIn, wsA, wsB);
  k_finish<<<32, 256, 0, stream>>>(wsA, wsB, out);
}

// Round 5
// 11998.666 us; speedup vs baseline: 1.1442x; 1.1442x over previous
//
#include <hip/hip_runtime.h>
#include <cstdint>
#include <cstddef>

#define LSEQ 8192
#define NT   34
#define NP   36
#define SCH  64
#define CCH  128
#define F_L2E 1.4426950408889634f
#define F_LN2 0.6931471805599453f

#if __has_builtin(__builtin_amdgcn_sdot4)
#define DOT4(a,b,c) __builtin_amdgcn_sdot4((a),(b),(c),false)
#else
__device__ __forceinline__ int dot4_fb(int a,int b,int c){
  c += (int)(signed char)(a & 0xff)        * (int)(signed char)(b & 0xff);
  c += (int)(signed char)((a>>8) & 0xff)   * (int)(signed char)((b>>8) & 0xff);
  c += (int)(signed char)((a>>16) & 0xff)  * (int)(signed char)((b>>16) & 0xff);
  c += (a>>24) * (b>>24);
  return c;
}
#define DOT4(a,b,c) dot4_fb((a),(b),(c))
#endif

__device__ __forceinline__ float ex2(float x){ return exp2f(x); }
__device__ __forceinline__ float lg2(float x){ return __log2f(x); }

__device__ __forceinline__ float sigf(float x){
  return __fdividef(1.f, 1.f + ex2(-F_L2E * x));
}
__device__ __forceinline__ float tanhf_fast(float x){
  return 1.f - __fdividef(2.f, ex2(2.f * F_L2E * x) + 1.f);
}

// barrier without the vmcnt(0) drain: LDS-only fence + s_barrier.
__device__ __forceinline__ void barrier_lds(){
  asm volatile("s_waitcnt lgkmcnt(0)\n\ts_barrier" ::: "memory");
}

// pair-swap within quad via DPP (VALU pipe, not LDS): lanes 0<->1, 2<->3
__device__ __forceinline__ float dpp_swap1(float x){
  int r = __builtin_amdgcn_mov_dpp(__float_as_int(x), 0xB1, 0xF, 0xF, true);
  return __int_as_float(r);
}

// force value to stay live in a VGPR (defeat rematerialization/reload)
#define PIN4(v) asm volatile("" : "+v"((v).x), "+v"((v).y), "+v"((v).z), "+v"((v).w))

// ---------------------------------------------------------------------------
// Kernel 1: quantize Whh (both dirs) to int8 per-row. Wq: [dir][row r][64 dw]
// facP layout: [dir][u*4 + pos], pos order (i,g,f,o)
// ---------------------------------------------------------------------------
__global__ void k_quant(const float* __restrict__ Whh_f,
                        const float* __restrict__ Whh_b,
                        int* __restrict__ Wq, float* __restrict__ facP){
  int bid = blockIdx.x;
  int dir = bid >> 10;
  int r   = bid & 1023;
  int i   = threadIdx.x;           // 0..63
  const float* W = (dir ? Whh_b : Whh_f) + r * 256 + i * 4;
  float w0 = W[0], w1 = W[1], w2 = W[2], w3 = W[3];
  float m = fmaxf(fmaxf(fabsf(w0), fabsf(w1)), fmaxf(fabsf(w2), fabsf(w3)));
  for (int s = 32; s; s >>= 1) m = fmaxf(m, __shfl_xor(m, s));
  float scale = (m > 0.f) ? m / 127.f : 1.f;
  float inv = __fdividef(1.f, scale);
  int q0 = (int)rintf(w0 * inv), q1 = (int)rintf(w1 * inv);
  int q2 = (int)rintf(w2 * inv), q3 = (int)rintf(w3 * inv);
  q0 = max(-127, min(127, q0)); q1 = max(-127, min(127, q1));
  q2 = max(-127, min(127, q2)); q3 = max(-127, min(127, q3));
  int p = (q0 & 255) | ((q1 & 255) << 8) | ((q2 & 255) << 16) | ((q3 & 255) << 24);
  Wq[(dir << 16) + (r << 6) + i] = p;
  if (i == 0) {
    int gi = r >> 8, u = r & 255;                 // gi: 0=i,1=f,2=g,3=o
    int pos = ((gi & 1) << 1) | (gi >> 1);        // i->0, g->1, f->2, o->3
    facP[(dir << 10) + u * 4 + pos] = scale * (1.f / 127.f);
  }
}

// ---------------------------------------------------------------------------
// Kernel 2: G[t][u*4 + (i,g,f,o)] = b + x @ Wih.T  (gate-interleaved, igfo)
// ---------------------------------------------------------------------------
__global__ void k_gproj(const int* __restrict__ words,
                        const float* __restrict__ embed,
                        const float* __restrict__ Wih_f, const float* __restrict__ b_f,
                        const float* __restrict__ Wih_b, const float* __restrict__ b_b,
                        float* __restrict__ G_f, float* __restrict__ G_b){
  int dir = blockIdx.y;
  const float* Wih = dir ? Wih_b : Wih_f;
  const float* bb  = dir ? b_b  : b_f;
  float* G = dir ? G_b : G_f;
  int t0 = blockIdx.x * 16;
  int uu = threadIdx.x;            // unit 0..255
  __shared__ __align__(16) float X[16 * 256];
  for (int idx = threadIdx.x; idx < 16 * 256; idx += 256) {
    int tt = idx >> 8, e = idx & 255;
    X[idx] = embed[(size_t)words[t0 + tt] * 256 + e];
  }
  __syncthreads();
  const float4* X4 = (const float4*)X;
  const float4* Wr0 = (const float4*)(Wih + (size_t)(uu)       * 256);  // i
  const float4* Wr1 = (const float4*)(Wih + (size_t)(uu + 256) * 256);  // f
  const float4* Wr2 = (const float4*)(Wih + (size_t)(uu + 512) * 256);  // g
  const float4* Wr3 = (const float4*)(Wih + (size_t)(uu + 768) * 256);  // o
  float b0 = bb[uu], b1 = bb[uu + 256], b2 = bb[uu + 512], b3 = bb[uu + 768];
  for (int pass = 0; pass < 2; pass++) {
    float4 acc[8];
#pragma unroll
    for (int tt = 0; tt < 8; tt++) acc[tt] = make_float4(b0, b1, b2, b3);
    for (int eb = 0; eb < 64; eb++) {
      float4 w0 = Wr0[eb], w1 = Wr1[eb], w2 = Wr2[eb], w3 = Wr3[eb];
#pragma unroll
      for (int tt = 0; tt < 8; tt++) {
        float4 x = X4[(pass * 8 + tt) * 64 + eb];
        acc[tt].x += w0.x * x.x + w0.y * x.y + w0.z * x.z + w0.w * x.w;
        acc[tt].y += w1.x * x.x + w1.y * x.y + w1.z * x.z + w1.w * x.w;
        acc[tt].z += w2.x * x.x + w2.y * x.y + w2.z * x.z + w2.w * x.w;
        acc[tt].w += w3.x * x.x + w3.y * x.y + w3.z * x.z + w3.w * x.w;
      }
    }
#pragma unroll
    for (int tt = 0; tt < 8; tt++) {
      // store order (i, g, f, o)
      float4 o4 = make_float4(acc[tt].x, acc[tt].z, acc[tt].y, acc[tt].w);
      *(float4*)(G + (size_t)(t0 + pass * 8 + tt) * 1024 + uu * 4) = o4;
    }
  }
}

// ---------------------------------------------------------------------------
// Kernel 3: LSTM recurrence. 512 threads (8 waves), 2 waves/SIMD.
// Thread 2u owns gate rows (i,g) of unit u; thread 2u+1 owns (f,o).
// Weights PINNED in VGPRs (asm). h broadcast: 1 lane-distinct ds_read_b32
// per wave + 64 v_readlane -> SGPRs. Pair exchange via DPP quad_perm.
// ONE lgkm barrier/step, double-buffered int8 h.
// ---------------------------------------------------------------------------
__global__ __launch_bounds__(512, 2) void k_lstm5(const int* __restrict__ Wq,
                                                  const float* __restrict__ facP,
                                                  const float* __restrict__ G_f,
                                                  const float* __restrict__ G_b,
                                                  float* __restrict__ hf,
                                                  float* __restrict__ hb){
  int dir = blockIdx.x;
  const int* Wqd = Wq + (dir << 16);
  const float* G = dir ? G_b : G_f;
  float* hout = dir ? hb : hf;
  int tid = threadIdx.x;
  int l = tid & 63;
  int u = tid >> 1;                 // unit 0..255
  bool ev = (tid & 1) == 0;

  __shared__ __align__(16) int h8i[2 * 64];   // two 256-byte int8 h buffers

  // rows: even -> u (i) and 512+u (g); odd -> 256+u (f) and 768+u (o)
  int rA = ((tid & 1) << 8) + u;
  int rB = rA + 512;
  int4 wA[16], wB[16];
  {
    const int4* pa = (const int4*)(Wqd + rA * 64);
    const int4* pb = (const int4*)(Wqd + rB * 64);
#pragma unroll
    for (int kt = 0; kt < 16; kt++) {
      wA[kt] = pa[kt]; PIN4(wA[kt]);
      wB[kt] = pb[kt]; PIN4(wB[kt]);
    }
  }

  int goff = u * 4 + ((tid & 1) << 1);      // (i,g) or (f,o) pair offset
  float2 fv = *(const float2*)(facP + (dir << 10) + goff);

  int time0 = dir ? 8191 : 0;
  int time1 = dir ? 8190 : 1;
  float2 gcur = *(const float2*)(G + (size_t)time0 * 1024 + goff);
  float2 gnxt = *(const float2*)(G + (size_t)time1 * 1024 + goff);

  if (tid < 128) h8i[tid] = 0;
  float c = 0.f;
  __syncthreads();

  for (int t = 0; t < 8192; t++) {
    // prefetch G two steps ahead (overlaps dot phase)
    int tn2 = (t + 2 < 8192) ? t + 2 : 8191;
    int time2 = dir ? (8191 - tn2) : tn2;
    float2 gpre = *(const float2*)(G + (size_t)time2 * 1024 + goff);

    int p = t & 1;
    // lane-distinct read: lane l holds h dword l of buffer p
    int hdw = h8i[p * 64 + l];
    int hs[64];
#pragma unroll
    for (int k = 0; k < 64; k++) hs[k] = __builtin_amdgcn_readlane(hdw, k);

    int accA = 0, accB = 0;
#pragma unroll
    for (int kt = 0; kt < 16; kt++) {
      accA = DOT4(wA[kt].x, hs[4*kt+0], accA);
      accA = DOT4(wA[kt].y, hs[4*kt+1], accA);
      accA = DOT4(wA[kt].z, hs[4*kt+2], accA);
      accA = DOT4(wA[kt].w, hs[4*kt+3], accA);
      accB = DOT4(wB[kt].x, hs[4*kt+0], accB);
      accB = DOT4(wB[kt].y, hs[4*kt+1], accB);
      accB = DOT4(wB[kt].z, hs[4*kt+2], accB);
      accB = DOT4(wB[kt].w, hs[4*kt+3], accB);
    }
    float aA = (float)accA * fv.x + gcur.x;   // even: i   odd: f
    float aB = (float)accB * fv.y + gcur.y;   // even: g   odd: o

    float pA = dpp_swap1(aA);
    float pB = dpp_swap1(aB);
    float ri = ev ? aA : pA;
    float rf = ev ? pA : aA;
    float rg = ev ? aB : pB;
    float ro = ev ? pB : aB;

    float is = sigf(ri), fs = sigf(rf);
    float gt = tanhf_fast(rg), os = sigf(ro);
    c = fs * c + is * gt;                     // identical across the pair
    float h = os * tanhf_fast(c);

    int time = dir ? (8191 - t) : t;
    if (ev) {
      hout[(size_t)time * 256 + u] = h;
      ((signed char*)h8i)[(p ^ 1) * 256 + u] = (signed char)(int)rintf(h * 127.f);
    }
    gcur = gnxt; gnxt = gpre;
    barrier_lds();
  }
}

// ---------------------------------------------------------------------------
// Kernel 4: feats = [hf | hb] @ W_out.T + b_out.
// ---------------------------------------------------------------------------
__global__ void k_feats(const float* __restrict__ hf, const float* __restrict__ hb,
                        const float* __restrict__ W_out, const float* __restrict__ b_out,
                        float* __restrict__ feats){
  int t0 = blockIdx.x * 16;
  for (int oi = threadIdx.x; oi < 16 * NT; oi += 256) {
    int tt = oi / NT;
    int tag = oi - tt * NT;
    int t = t0 + tt;
    const float4* w4 = (const float4*)(W_out + (size_t)tag * 512);
    const float4* a4 = (const float4*)(hf + (size_t)t * 256);
    const float4* c4 = (const float4*)(hb + (size_t)t * 256);
    float acc = b_out[tag];
    for (int k = 0; k < 64; k++) {
      float4 w = w4[k]; float4 h = a4[k];
      acc += w.x * h.x + w.y * h.y + w.z * h.z + w.w * h.w;
    }
    for (int k = 0; k < 64; k++) {
      float4 w = w4[64 + k]; float4 h = c4[k];
      acc += w.x * h.x + w.y * h.y + w.z * h.z + w.w * h.w;
    }
    feats[(size_t)t * NT + tag] = acc;
  }
}

// ---------------------------------------------------------------------------
// CRF chunked associative scan, (lse,+) semiring, log2-domain (unchanged).
// ---------------------------------------------------------------------------
__global__ __launch_bounds__(320) void k_crf_p1(const float* __restrict__ feats,
                                                const float* __restrict__ trans,
                                                float* __restrict__ Pg,
                                                float* __restrict__ rmaxG){
  int dir = blockIdx.x >> 7;
  int c   = blockIdx.x & (CCH - 1);
  int tid = threadIdx.x;
  int t0  = c * SCH;

  __shared__ __align__(16) float TRM[NT * NP];
  __shared__ float Fe[(SCH + 1) * NT];
  __shared__ __align__(16) float Pbuf[2][NT * NP];
  __shared__ float CM[NP];
  __shared__ float RMs[NT];

  for (int idx = tid; idx < NT * NT; idx += 320) {
    int j = idx / NT, k = idx - j * NT;
    float v = (dir == 0) ? trans[j * NT + k] : trans[k * NT + j];
    TRM[j * NP + k] = v * F_L2E;
  }
  for (int idx = tid; idx < (SCH + 1) * NT; idx += 320) {
    int s = idx / NT, j = idx - s * NT;
    int t = t0 + s; if (t > LSEQ - 1) t = LSEQ - 1;
    Fe[idx] = feats[(size_t)t * NT + j] * F_L2E;
  }
  for (int idx = tid; idx < NT * NP; idx += 320) {
    int k = idx / NP, i = idx - k * NP;
    Pbuf[0][idx] = (i < NT && i == k) ? 0.f : -1e30f;
  }
  if (tid < NP) CM[tid] = (tid < NT) ? 0.f : -1e30f;
  __syncthreads();
  if (tid < NT) {
    float m = -3e38f;
    for (int k = 0; k < NT; k++) m = fmaxf(m, TRM[tid * NP + k]);
    RMs[tid] = m;
  }
  __syncthreads();
  for (int idx = tid; idx < NT * NT; idx += 320) {
    int j = idx / NT, k = idx - j * NT;
    TRM[j * NP + k] -= RMs[j];
  }
  __syncthreads();

  int cur = 0;
  int j = tid / 9, g = tid - (tid / 9) * 9;
  bool act = (tid < 306);
  int i0 = 4 * g;

  for (int s = 0; s < SCH; s++) {
    int t = (dir == 0) ? (t0 + s) : (t0 + SCH - 1 - s);
    if (dir == 1 && t == LSEQ - 1) continue;   // identity factor at t=L-1
    const float* Pc = Pbuf[cur];
    float* Pn = Pbuf[cur ^ 1];
    if (act) {
      float cm0 = CM[i0], cm1 = CM[i0 + 1], cm2 = CM[i0 + 2], cm3 = CM[i0 + 3];
      float s0 = 0, s1 = 0, s2 = 0, s3 = 0;
      const float* trp = TRM + j * NP;
      const float* fep = Fe + (t + 1 - t0) * NT;
#pragma unroll
      for (int k = 0; k < NT; k++) {
        float trv = trp[k];
        if (dir == 1) trv += fep[k];
        float4 p = *(const float4*)&Pc[k * NP + i0];
        s0 += ex2(trv + p.x - cm0);
        s1 += ex2(trv + p.y - cm1);
        s2 += ex2(trv + p.z - cm2);
        s3 += ex2(trv + p.w - cm3);
      }
      float base = RMs[j] + ((dir == 0) ? Fe[(t - t0) * NT + j] : 0.f);
      float4 o;
      o.x = base + cm0 + lg2(s0);
      o.y = base + cm1 + lg2(s1);
      o.z = (i0 + 2 < NT) ? (base + cm2 + lg2(s2)) : -1e30f;
      o.w = (i0 + 3 < NT) ? (base + cm3 + lg2(s3)) : -1e30f;
      *(float4*)&Pn[j * NP + i0] = o;
    }
    __syncthreads();
    if (tid < NP) {
      float m = -3e38f;
      const float* colp = Pn + tid;
      for (int k = 0; k < NT; k++) m = fmaxf(m, colp[k * NP]);
      CM[tid] = m;
    }
    cur ^= 1;
    __syncthreads();
  }

  const float* Pf = Pbuf[cur];
  size_t base = (size_t)((dir << 7) + c) * (NT * NP);
  for (int idx = tid; idx < NT * NP; idx += 320)
    Pg[base + idx] = Pf[idx];
  if (tid < NT) {
    float m = -3e38f;
    for (int i = 0; i < NT; i++) m = fmaxf(m, Pf[tid * NP + i]);
    rmaxG[((dir << 7) + c) * NT + tid] = m;
  }
}

__global__ void k_crf_p2(const float* __restrict__ trans,
                         const float* __restrict__ Pg,
                         const float* __restrict__ rmaxG,
                         float* __restrict__ vIn){
  int dir = blockIdx.x;
  int lane = threadIdx.x;           // 64, single wave
  bool a = (lane < NT);
  int j = a ? lane : 0;
  __shared__ float V[NP];

  float v;
  if (dir == 0) {
    v = (lane == 32) ? 0.f : -10000.f * F_L2E;
  } else {
    float m = -3e38f;
    for (int i = 0; i < NT; i++) m = fmaxf(m, trans[i * NT + j]);
    float s = 0.f;
    for (int i = 0; i < NT; i++) s += ex2((trans[i * NT + j] - m) * F_L2E);
    v = m * F_L2E + lg2(s);
  }
  if (lane < NP) V[lane] = -1e30f;
  barrier_lds();
  if (a) V[j] = v;
  barrier_lds();
  float vm = a ? v : -3e38f;
  for (int off = 32; off; off >>= 1) vm = fmaxf(vm, __shfl_xor(vm, off));

  if (a) {
    int c0 = (dir == 0) ? 0 : (CCH - 1);
    vIn[((size_t)(dir << 7) + c0) * NP + j] = v;
  }

  for (int it = 0; it < CCH - 1; it++) {
    int c = (dir == 0) ? it : (CCH - 1 - it);
    const float* row = Pg + ((size_t)(dir << 7) + c) * (NT * NP) + j * NP;
    float rm = rmaxG[((dir << 7) + c) * NT + j];
    float m = rm + vm;
    float s = 0.f;
#pragma unroll
    for (int k = 0; k < NP; k += 4) {
      float4 p = *(const float4*)&row[k];
      s += ex2(p.x + V[k]     - m);
      s += ex2(p.y + V[k + 1] - m);
      s += ex2(p.z + V[k + 2] - m);
      s += ex2(p.w + V[k + 3] - m);
    }
    float nv = m + lg2(s);
    if (a) V[j] = nv;
    barrier_lds();
    float x = a ? nv : -3e38f;
    for (int off = 32; off; off >>= 1) x = fmaxf(x, __shfl_xor(x, off));
    vm = x;
    int cn = (dir == 0) ? (c + 1) : (c - 1);
    if (a) vIn[((size_t)(dir << 7) + cn) * NP + j] = nv;
  }
}

__global__ void k_crf_p3(const float* __restrict__ feats,
                         const float* __restrict__ trans,
                         const float* __restrict__ vIn,
                         float* __restrict__ wsA,
                         float* __restrict__ wsB){
  int dir = blockIdx.x >> 7;
  int c   = blockIdx.x & (CCH - 1);
  int lane = threadIdx.x;           // 64, single wave
  int t0 = c * SCH;
  bool a = (lane < NT);
  int j = a ? lane : 0;
  __shared__ float A[NP];
  __shared__ float U[NP];

  float trr[NT];
  float rm = -3e38f;
#pragma unroll
  for (int k = 0; k < NT; k++) {
    float vv = (dir == 0) ? trans[j * NT + k] : trans[k * NT + j];
    trr[k] = vv * F_L2E;
    rm = fmaxf(rm, trr[k]);
  }
  if (lane < NP) { A[lane] = -1e30f; U[lane] = -1e30f; }
  float v0 = vIn[((size_t)(dir << 7) + c) * NP + j];
  barrier_lds();
  if (a) A[j] = v0;
  barrier_lds();
  float am = a ? v0 : -3e38f;
  for (int off = 32; off; off >>= 1) am = fmaxf(am, __shfl_xor(am, off));

  if (dir == 0) {
    float fe = feats[(size_t)t0 * NT + j] * F_L2E;
    for (int s = 0; s < SCH; s++) {
      int t = t0 + s;
      int tn = (t + 1 < LSEQ) ? t + 1 : LSEQ - 1;
      float fe_n = feats[(size_t)tn * NT + j] * F_L2E;
      float m = rm + am;
      float ss = 0.f;
#pragma unroll
      for (int k = 0; k < NT; k++) ss += ex2(trr[k] + A[k] - m);
      float out = m + lg2(ss) + fe;
      if (a) wsA[(size_t)t * NT + j] = out * F_LN2;
      if (a) A[j] = out;
      barrier_lds();
      float x = a ? out : -3e38f;
      for (int off = 32; off; off >>= 1) x = fmaxf(x, __shfl_xor(x, off));
      am = x;
      fe = fe_n;
    }
  } else {
    float b = v0;
    int tfirst = t0 + SCH; if (tfirst > LSEQ - 1) tfirst = LSEQ - 1;
    float fe = feats[(size_t)tfirst * NT + j] * F_L2E;
    for (int s = 0; s < SCH; s++) {
      int t = t0 + SCH - 1 - s;
      float fe_n = feats[(size_t)t * NT + j] * F_L2E;
      float out;
      if (t == LSEQ - 1) {
        out = b;
      } else {
        if (a) U[j] = b + fe;
        barrier_lds();
        float um = a ? U[j] : -3e38f;
        for (int off = 32; off; off >>= 1) um = fmaxf(um, __shfl_xor(um, off));
        float m = rm + um;
        float ss = 0.f;
#pragma unroll
        for (int k = 0; k < NT; k++) ss += ex2(trr[k] + U[k] - m);
        out = m + lg2(ss);
        barrier_lds();
      }
      if (a) wsB[(size_t)t * NT + j] = out * F_LN2;
      b = out;
      fe = fe_n;
    }
  }
}

// ---------------------------------------------------------------------------
__global__ void k_finish(const float* __restrict__ wsA, const float* __restrict__ wsB,
                         float* __restrict__ out){
  int t = blockIdx.x * 256 + threadIdx.x;
  float m = -3e38f; int bi = 0;
  for (int i = 0; i < NT; i++) {
    float sc = wsA[(size_t)t * NT + i] + wsB[(size_t)t * NT + i];
    out[(size_t)t * NT + i] = sc;
    if (sc > m) { m = sc; bi = i; }
  }
  out[(size_t)LSEQ * NT + t] = (float)bi;
}

// ---------------------------------------------------------------------------
extern "C" void kernel_launch(void* const* d_in, const int* in_sizes, int n_in,
                              void* d_out, int out_size, void* d_ws, size_t ws_size,
                              hipStream_t stream) {
  const int*   words  = (const int*)  d_in[0];
  const float* embed  = (const float*)d_in[1];
  const float* Wih_f  = (const float*)d_in[2];
  const float* Whh_f  = (const float*)d_in[3];
  const float* b_f    = (const float*)d_in[4];
  const float* Wih_b  = (const float*)d_in[5];
  const float* Whh_b  = (const float*)d_in[6];
  const float* b_b    = (const float*)d_in[7];
  const float* W_out  = (const float*)d_in[8];
  const float* b_out  = (const float*)d_in[9];
  const float* trans  = (const float*)d_in[10];
  float* out = (float*)d_out;

  float* wsf = (float*)d_ws;
  size_t off = 0;
  float* G_f   = wsf + off; off += (size_t)LSEQ * 1024;
  float* G_b   = wsf + off; off += (size_t)LSEQ * 1024;
  float* hf    = wsf + off; off += (size_t)LSEQ * 256;
  float* hb    = wsf + off; off += (size_t)LSEQ * 256;
  float* feats = wsf + off; off += (size_t)LSEQ * NT + 16;
  float* wsA   = wsf + off; off += (size_t)LSEQ * NT + 16;
  float* wsB   = wsf + off; off += (size_t)LSEQ * NT + 16;
  float* facP  = wsf + off; off += 2048;
  int*   Wq    = (int*)(wsf + off); off += 2 * 1024 * 64;
  // CRF scan scratch overlaps G_f (dead after k_lstm5)
  float* Pg    = G_f;
  float* rmaxG = G_f + 256 * (NT * NP);
  float* vIn   = rmaxG + 256 * NT + 32;

  k_quant<<<2048, 64, 0, stream>>>(Whh_f, Whh_b, Wq, facP);
  k_gproj<<<dim3(512, 2), 256, 0, stream>>>(words, embed, Wih_f, b_f, Wih_b, b_b, G_f, G_b);
  k_lstm5<<<2, 512, 0, stream>>>(Wq, facP, G_f, G_b, hf, hb);
  k_feats<<<512, 256, 0, stream>>>(hf, hb, W_out, b_out, feats);
  k_crf_p1<<<256, 320, 0, stream>>>(feats, trans, Pg, rmaxG);
  k_crf_p2<<<2, 64, 0, stream>>>(trans, Pg, rmaxG, vIn);
  k_crf_p3<<<256, 64, 0, stream>>>(feats, trans, vIn, wsA, wsB);
  k_finish<<<32, 256, 0, stream>>>(wsA, wsB, out);
}

// Round 6
// 11794.081 us; speedup vs baseline: 1.1640x; 1.0173x over previous
//
#include <hip/hip_runtime.h>
#include <cstdint>
#include <cstddef>

#define LSEQ 8192
#define NT   34
#define NP   36
#define SCH  64
#define CCH  128
#define F_L2E 1.4426950408889634f
#define F_LN2 0.6931471805599453f

#if __has_builtin(__builtin_amdgcn_sdot4)
#define DOT4(a,b,c) __builtin_amdgcn_sdot4((a),(b),(c),false)
#else
__device__ __forceinline__ int dot4_fb(int a,int b,int c){
  c += (int)(signed char)(a & 0xff)        * (int)(signed char)(b & 0xff);
  c += (int)(signed char)((a>>8) & 0xff)   * (int)(signed char)((b>>8) & 0xff);
  c += (int)(signed char)((a>>16) & 0xff)  * (int)(signed char)((b>>16) & 0xff);
  c += (a>>24) * (b>>24);
  return c;
}
#define DOT4(a,b,c) dot4_fb((a),(b),(c))
#endif

__device__ __forceinline__ float ex2(float x){ return exp2f(x); }
__device__ __forceinline__ float lg2(float x){ return __log2f(x); }

__device__ __forceinline__ float sigf(float x){
  return __fdividef(1.f, 1.f + ex2(-F_L2E * x));
}
__device__ __forceinline__ float tanhf_fast(float x){
  return 1.f - __fdividef(2.f, ex2(2.f * F_L2E * x) + 1.f);
}

// barrier without the vmcnt(0) drain: LDS-only fence + s_barrier.
__device__ __forceinline__ void barrier_lds(){
  asm volatile("s_waitcnt lgkmcnt(0)\n\ts_barrier" ::: "memory");
}

// pair-swap within quad via DPP (VALU pipe, not LDS): lanes 0<->1, 2<->3
__device__ __forceinline__ float dpp_swap1(float x){
  int r = __builtin_amdgcn_mov_dpp(__float_as_int(x), 0xB1, 0xF, 0xF, true);
  return __int_as_float(r);
}

// In-loop VGPR pin: asm "may modify" these every iteration, so a reload from
// memory is no longer a legal rematerialization -- values MUST stay live in
// VGPRs across the loop back-edge. Zero instructions emitted.
#define PIN8(a,b) asm volatile("" : "+v"((a).x), "+v"((a).y), "+v"((a).z), "+v"((a).w), \
                                    "+v"((b).x), "+v"((b).y), "+v"((b).z), "+v"((b).w))

// ---------------------------------------------------------------------------
// Kernel 1: quantize Whh (both dirs) to int8 per-row. Wq: [dir][row r][64 dw]
// facP layout: [dir][u*4 + pos], pos order (i,g,f,o)
// ---------------------------------------------------------------------------
__global__ void k_quant(const float* __restrict__ Whh_f,
                        const float* __restrict__ Whh_b,
                        int* __restrict__ Wq, float* __restrict__ facP){
  int bid = blockIdx.x;
  int dir = bid >> 10;
  int r   = bid & 1023;
  int i   = threadIdx.x;           // 0..63
  const float* W = (dir ? Whh_b : Whh_f) + r * 256 + i * 4;
  float w0 = W[0], w1 = W[1], w2 = W[2], w3 = W[3];
  float m = fmaxf(fmaxf(fabsf(w0), fabsf(w1)), fmaxf(fabsf(w2), fabsf(w3)));
  for (int s = 32; s; s >>= 1) m = fmaxf(m, __shfl_xor(m, s));
  float scale = (m > 0.f) ? m / 127.f : 1.f;
  float inv = __fdividef(1.f, scale);
  int q0 = (int)rintf(w0 * inv), q1 = (int)rintf(w1 * inv);
  int q2 = (int)rintf(w2 * inv), q3 = (int)rintf(w3 * inv);
  q0 = max(-127, min(127, q0)); q1 = max(-127, min(127, q1));
  q2 = max(-127, min(127, q2)); q3 = max(-127, min(127, q3));
  int p = (q0 & 255) | ((q1 & 255) << 8) | ((q2 & 255) << 16) | ((q3 & 255) << 24);
  Wq[(dir << 16) + (r << 6) + i] = p;
  if (i == 0) {
    int gi = r >> 8, u = r & 255;                 // gi: 0=i,1=f,2=g,3=o
    int pos = ((gi & 1) << 1) | (gi >> 1);        // i->0, g->1, f->2, o->3
    facP[(dir << 10) + u * 4 + pos] = scale * (1.f / 127.f);
  }
}

// ---------------------------------------------------------------------------
// Kernel 2: G[t][u*4 + (i,g,f,o)] = b + x @ Wih.T  (gate-interleaved, igfo)
// ---------------------------------------------------------------------------
__global__ void k_gproj(const int* __restrict__ words,
                        const float* __restrict__ embed,
                        const float* __restrict__ Wih_f, const float* __restrict__ b_f,
                        const float* __restrict__ Wih_b, const float* __restrict__ b_b,
                        float* __restrict__ G_f, float* __restrict__ G_b){
  int dir = blockIdx.y;
  const float* Wih = dir ? Wih_b : Wih_f;
  const float* bb  = dir ? b_b  : b_f;
  float* G = dir ? G_b : G_f;
  int t0 = blockIdx.x * 16;
  int uu = threadIdx.x;            // unit 0..255
  __shared__ __align__(16) float X[16 * 256];
  for (int idx = threadIdx.x; idx < 16 * 256; idx += 256) {
    int tt = idx >> 8, e = idx & 255;
    X[idx] = embed[(size_t)words[t0 + tt] * 256 + e];
  }
  __syncthreads();
  const float4* X4 = (const float4*)X;
  const float4* Wr0 = (const float4*)(Wih + (size_t)(uu)       * 256);  // i
  const float4* Wr1 = (const float4*)(Wih + (size_t)(uu + 256) * 256);  // f
  const float4* Wr2 = (const float4*)(Wih + (size_t)(uu + 512) * 256);  // g
  const float4* Wr3 = (const float4*)(Wih + (size_t)(uu + 768) * 256);  // o
  float b0 = bb[uu], b1 = bb[uu + 256], b2 = bb[uu + 512], b3 = bb[uu + 768];
  for (int pass = 0; pass < 2; pass++) {
    float4 acc[8];
#pragma unroll
    for (int tt = 0; tt < 8; tt++) acc[tt] = make_float4(b0, b1, b2, b3);
    for (int eb = 0; eb < 64; eb++) {
      float4 w0 = Wr0[eb], w1 = Wr1[eb], w2 = Wr2[eb], w3 = Wr3[eb];
#pragma unroll
      for (int tt = 0; tt < 8; tt++) {
        float4 x = X4[(pass * 8 + tt) * 64 + eb];
        acc[tt].x += w0.x * x.x + w0.y * x.y + w0.z * x.z + w0.w * x.w;
        acc[tt].y += w1.x * x.x + w1.y * x.y + w1.z * x.z + w1.w * x.w;
        acc[tt].z += w2.x * x.x + w2.y * x.y + w2.z * x.z + w2.w * x.w;
        acc[tt].w += w3.x * x.x + w3.y * x.y + w3.z * x.z + w3.w * x.w;
      }
    }
#pragma unroll
    for (int tt = 0; tt < 8; tt++) {
      // store order (i, g, f, o)
      float4 o4 = make_float4(acc[tt].x, acc[tt].z, acc[tt].y, acc[tt].w);
      *(float4*)(G + (size_t)(t0 + pass * 8 + tt) * 1024 + uu * 4) = o4;
    }
  }
}

// ---------------------------------------------------------------------------
// Kernel 3: LSTM recurrence. 512 threads (8 waves), 2 waves/SIMD.
// Thread 2u owns gate rows (i,g) of unit u; thread 2u+1 owns (f,o).
// Weights pinned in VGPRs via IN-LOOP asm (reload is not a legal remat).
// h broadcast: 1 lane-distinct ds_read_b32 per wave + 64 v_readlane -> SGPRs.
// Pair exchange via DPP quad_perm. ONE lgkm barrier/step, dbuf int8 h.
// ---------------------------------------------------------------------------
__global__ __launch_bounds__(512, 2) void k_lstm6(const int* __restrict__ Wq,
                                                  const float* __restrict__ facP,
                                                  const float* __restrict__ G_f,
                                                  const float* __restrict__ G_b,
                                                  float* __restrict__ hf,
                                                  float* __restrict__ hb){
  int dir = blockIdx.x;
  const int* Wqd = Wq + (dir << 16);
  const float* G = dir ? G_b : G_f;
  float* hout = dir ? hb : hf;
  int tid = threadIdx.x;
  int l = tid & 63;
  int u = tid >> 1;                 // unit 0..255
  bool ev = (tid & 1) == 0;

  __shared__ __align__(16) int h8i[2 * 64];   // two 256-byte int8 h buffers

  // rows: even -> u (i) and 512+u (g); odd -> 256+u (f) and 768+u (o)
  int rA = ((tid & 1) << 8) + u;
  int rB = rA + 512;
  int4 wA[16], wB[16];
  {
    const int4* pa = (const int4*)(Wqd + rA * 64);
    const int4* pb = (const int4*)(Wqd + rB * 64);
#pragma unroll
    for (int kt = 0; kt < 16; kt++) { wA[kt] = pa[kt]; wB[kt] = pb[kt]; }
  }

  int goff = u * 4 + ((tid & 1) << 1);      // (i,g) or (f,o) pair offset
  float2 fv = *(const float2*)(facP + (dir << 10) + goff);

  int time0 = dir ? 8191 : 0;
  int time1 = dir ? 8190 : 1;
  float2 gcur = *(const float2*)(G + (size_t)time0 * 1024 + goff);
  float2 gnxt = *(const float2*)(G + (size_t)time1 * 1024 + goff);

  if (tid < 128) h8i[tid] = 0;
  float c = 0.f;
  __syncthreads();

  for (int t = 0; t < 8192; t++) {
    // the pin: forces all 128 weight dwords live in VGPRs every iteration
#pragma unroll
    for (int kt = 0; kt < 16; kt++) PIN8(wA[kt], wB[kt]);

    // prefetch G two steps ahead (overlaps dot phase)
    int tn2 = (t + 2 < 8192) ? t + 2 : 8191;
    int time2 = dir ? (8191 - tn2) : tn2;
    float2 gpre = *(const float2*)(G + (size_t)time2 * 1024 + goff);

    int p = t & 1;
    // lane-distinct read: lane l holds h dword l of buffer p
    int hdw = h8i[p * 64 + l];
    int hs[64];
#pragma unroll
    for (int k = 0; k < 64; k++) hs[k] = __builtin_amdgcn_readlane(hdw, k);

    int accA = 0, accB = 0;
#pragma unroll
    for (int kt = 0; kt < 16; kt++) {
      accA = DOT4(wA[kt].x, hs[4*kt+0], accA);
      accA = DOT4(wA[kt].y, hs[4*kt+1], accA);
      accA = DOT4(wA[kt].z, hs[4*kt+2], accA);
      accA = DOT4(wA[kt].w, hs[4*kt+3], accA);
      accB = DOT4(wB[kt].x, hs[4*kt+0], accB);
      accB = DOT4(wB[kt].y, hs[4*kt+1], accB);
      accB = DOT4(wB[kt].z, hs[4*kt+2], accB);
      accB = DOT4(wB[kt].w, hs[4*kt+3], accB);
    }
    float aA = (float)accA * fv.x + gcur.x;   // even: i   odd: f
    float aB = (float)accB * fv.y + gcur.y;   // even: g   odd: o

    float pA = dpp_swap1(aA);
    float pB = dpp_swap1(aB);
    float ri = ev ? aA : pA;
    float rf = ev ? pA : aA;
    float rg = ev ? aB : pB;
    float ro = ev ? pB : aB;

    float is = sigf(ri), fs = sigf(rf);
    float gt = tanhf_fast(rg), os = sigf(ro);
    c = fs * c + is * gt;                     // identical across the pair
    float h = os * tanhf_fast(c);

    int time = dir ? (8191 - t) : t;
    if (ev) {
      hout[(size_t)time * 256 + u] = h;
      ((signed char*)h8i)[(p ^ 1) * 256 + u] = (signed char)(int)rintf(h * 127.f);
    }
    gcur = gnxt; gnxt = gpre;
    barrier_lds();
  }
}

// ---------------------------------------------------------------------------
// Kernel 4: feats = [hf | hb] @ W_out.T + b_out.
// ---------------------------------------------------------------------------
__global__ void k_feats(const float* __restrict__ hf, const float* __restrict__ hb,
                        const float* __restrict__ W_out, const float* __restrict__ b_out,
                        float* __restrict__ feats){
  int t0 = blockIdx.x * 16;
  for (int oi = threadIdx.x; oi < 16 * NT; oi += 256) {
    int tt = oi / NT;
    int tag = oi - tt * NT;
    int t = t0 + tt;
    const float4* w4 = (const float4*)(W_out + (size_t)tag * 512);
    const float4* a4 = (const float4*)(hf + (size_t)t * 256);
    const float4* c4 = (const float4*)(hb + (size_t)t * 256);
    float acc = b_out[tag];
    for (int k = 0; k < 64; k++) {
      float4 w = w4[k]; float4 h = a4[k];
      acc += w.x * h.x + w.y * h.y + w.z * h.z + w.w * h.w;
    }
    for (int k = 0; k < 64; k++) {
      float4 w = w4[64 + k]; float4 h = c4[k];
      acc += w.x * h.x + w.y * h.y + w.z * h.z + w.w * h.w;
    }
    feats[(size_t)t * NT + tag] = acc;
  }
}

// ---------------------------------------------------------------------------
// CRF chunked associative scan, (lse,+) semiring, log2-domain (unchanged).
// ---------------------------------------------------------------------------
__global__ __launch_bounds__(320) void k_crf_p1(const float* __restrict__ feats,
                                                const float* __restrict__ trans,
                                                float* __restrict__ Pg,
                                                float* __restrict__ rmaxG){
  int dir = blockIdx.x >> 7;
  int c   = blockIdx.x & (CCH - 1);
  int tid = threadIdx.x;
  int t0  = c * SCH;

  __shared__ __align__(16) float TRM[NT * NP];
  __shared__ float Fe[(SCH + 1) * NT];
  __shared__ __align__(16) float Pbuf[2][NT * NP];
  __shared__ float CM[NP];
  __shared__ float RMs[NT];

  for (int idx = tid; idx < NT * NT; idx += 320) {
    int j = idx / NT, k = idx - j * NT;
    float v = (dir == 0) ? trans[j * NT + k] : trans[k * NT + j];
    TRM[j * NP + k] = v * F_L2E;
  }
  for (int idx = tid; idx < (SCH + 1) * NT; idx += 320) {
    int s = idx / NT, j = idx - s * NT;
    int t = t0 + s; if (t > LSEQ - 1) t = LSEQ - 1;
    Fe[idx] = feats[(size_t)t * NT + j] * F_L2E;
  }
  for (int idx = tid; idx < NT * NP; idx += 320) {
    int k = idx / NP, i = idx - k * NP;
    Pbuf[0][idx] = (i < NT && i == k) ? 0.f : -1e30f;
  }
  if (tid < NP) CM[tid] = (tid < NT) ? 0.f : -1e30f;
  __syncthreads();
  if (tid < NT) {
    float m = -3e38f;
    for (int k = 0; k < NT; k++) m = fmaxf(m, TRM[tid * NP + k]);
    RMs[tid] = m;
  }
  __syncthreads();
  for (int idx = tid; idx < NT * NT; idx += 320) {
    int j = idx / NT, k = idx - j * NT;
    TRM[j * NP + k] -= RMs[j];
  }
  __syncthreads();

  int cur = 0;
  int j = tid / 9, g = tid - (tid / 9) * 9;
  bool act = (tid < 306);
  int i0 = 4 * g;

  for (int s = 0; s < SCH; s++) {
    int t = (dir == 0) ? (t0 + s) : (t0 + SCH - 1 - s);
    if (dir == 1 && t == LSEQ - 1) continue;   // identity factor at t=L-1
    const float* Pc = Pbuf[cur];
    float* Pn = Pbuf[cur ^ 1];
    if (act) {
      float cm0 = CM[i0], cm1 = CM[i0 + 1], cm2 = CM[i0 + 2], cm3 = CM[i0 + 3];
      float s0 = 0, s1 = 0, s2 = 0, s3 = 0;
      const float* trp = TRM + j * NP;
      const float* fep = Fe + (t + 1 - t0) * NT;
#pragma unroll
      for (int k = 0; k < NT; k++) {
        float trv = trp[k];
        if (dir == 1) trv += fep[k];
        float4 p = *(const float4*)&Pc[k * NP + i0];
        s0 += ex2(trv + p.x - cm0);
        s1 += ex2(trv + p.y - cm1);
        s2 += ex2(trv + p.z - cm2);
        s3 += ex2(trv + p.w - cm3);
      }
      float base = RMs[j] + ((dir == 0) ? Fe[(t - t0) * NT + j] : 0.f);
      float4 o;
      o.x = base + cm0 + lg2(s0);
      o.y = base + cm1 + lg2(s1);
      o.z = (i0 + 2 < NT) ? (base + cm2 + lg2(s2)) : -1e30f;
      o.w = (i0 + 3 < NT) ? (base + cm3 + lg2(s3)) : -1e30f;
      *(float4*)&Pn[j * NP + i0] = o;
    }
    __syncthreads();
    if (tid < NP) {
      float m = -3e38f;
      const float* colp = Pn + tid;
      for (int k = 0; k < NT; k++) m = fmaxf(m, colp[k * NP]);
      CM[tid] = m;
    }
    cur ^= 1;
    __syncthreads();
  }

  const float* Pf = Pbuf[cur];
  size_t base = (size_t)((dir << 7) + c) * (NT * NP);
  for (int idx = tid; idx < NT * NP; idx += 320)
    Pg[base + idx] = Pf[idx];
  if (tid < NT) {
    float m = -3e38f;
    for (int i = 0; i < NT; i++) m = fmaxf(m, Pf[tid * NP + i]);
    rmaxG[((dir << 7) + c) * NT + tid] = m;
  }
}

__global__ void k_crf_p2(const float* __restrict__ trans,
                         const float* __restrict__ Pg,
                         const float* __restrict__ rmaxG,
                         float* __restrict__ vIn){
  int dir = blockIdx.x;
  int lane = threadIdx.x;           // 64, single wave
  bool a = (lane < NT);
  int j = a ? lane : 0;
  __shared__ float V[NP];

  float v;
  if (dir == 0) {
    v = (lane == 32) ? 0.f : -10000.f * F_L2E;
  } else {
    float m = -3e38f;
    for (int i = 0; i < NT; i++) m = fmaxf(m, trans[i * NT + j]);
    float s = 0.f;
    for (int i = 0; i < NT; i++) s += ex2((trans[i * NT + j] - m) * F_L2E);
    v = m * F_L2E + lg2(s);
  }
  if (lane < NP) V[lane] = -1e30f;
  barrier_lds();
  if (a) V[j] = v;
  barrier_lds();
  float vm = a ? v : -3e38f;
  for (int off = 32; off; off >>= 1) vm = fmaxf(vm, __shfl_xor(vm, off));

  if (a) {
    int c0 = (dir == 0) ? 0 : (CCH - 1);
    vIn[((size_t)(dir << 7) + c0) * NP + j] = v;
  }

  for (int it = 0; it < CCH - 1; it++) {
    int c = (dir == 0) ? it : (CCH - 1 - it);
    const float* row = Pg + ((size_t)(dir << 7) + c) * (NT * NP) + j * NP;
    float rm = rmaxG[((dir << 7) + c) * NT + j];
    float m = rm + vm;
    float s = 0.f;
#pragma unroll
    for (int k = 0; k < NP; k += 4) {
      float4 p = *(const float4*)&row[k];
      s += ex2(p.x + V[k]     - m);
      s += ex2(p.y + V[k + 1] - m);
      s += ex2(p.z + V[k + 2] - m);
      s += ex2(p.w + V[k + 3] - m);
    }
    float nv = m + lg2(s);
    if (a) V[j] = nv;
    barrier_lds();
    float x = a ? nv : -3e38f;
    for (int off = 32; off; off >>= 1) x = fmaxf(x, __shfl_xor(x, off));
    vm = x;
    int cn = (dir == 0) ? (c + 1) : (c - 1);
    if (a) vIn[((size_t)(dir << 7) + cn) * NP + j] = nv;
  }
}

__global__ void k_crf_p3(const float* __restrict__ feats,
                         const float* __restrict__ trans,
                         const float* __restrict__ vIn,
                         float* __restrict__ wsA,
                         float* __restrict__ wsB){
  int dir = blockIdx.x >> 7;
  int c   = blockIdx.x & (CCH - 1);
  int lane = threadIdx.x;           // 64, single wave
  int t0 = c * SCH;
  bool a = (lane < NT);
  int j = a ? lane : 0;
  __shared__ float A[NP];
  __shared__ float U[NP];

  float trr[NT];
  float rm = -3e38f;
#pragma unroll
  for (int k = 0; k < NT; k++) {
    float vv = (dir == 0) ? trans[j * NT + k] : trans[k * NT + j];
    trr[k] = vv * F_L2E;
    rm = fmaxf(rm, trr[k]);
  }
  if (lane < NP) { A[lane] = -1e30f; U[lane] = -1e30f; }
  float v0 = vIn[((size_t)(dir << 7) + c) * NP + j];
  barrier_lds();
  if (a) A[j] = v0;
  barrier_lds();
  float am = a ? v0 : -3e38f;
  for (int off = 32; off; off >>= 1) am = fmaxf(am, __shfl_xor(am, off));

  if (dir == 0) {
    float fe = feats[(size_t)t0 * NT + j] * F_L2E;
    for (int s = 0; s < SCH; s++) {
      int t = t0 + s;
      int tn = (t + 1 < LSEQ) ? t + 1 : LSEQ - 1;
      float fe_n = feats[(size_t)tn * NT + j] * F_L2E;
      float m = rm + am;
      float ss = 0.f;
#pragma unroll
      for (int k = 0; k < NT; k++) ss += ex2(trr[k] + A[k] - m);
      float out = m + lg2(ss) + fe;
      if (a) wsA[(size_t)t * NT + j] = out * F_LN2;
      if (a) A[j] = out;
      barrier_lds();
      float x = a ? out : -3e38f;
      for (int off = 32; off; off >>= 1) x = fmaxf(x, __shfl_xor(x, off));
      am = x;
      fe = fe_n;
    }
  } else {
    float b = v0;
    int tfirst = t0 + SCH; if (tfirst > LSEQ - 1) tfirst = LSEQ - 1;
    float fe = feats[(size_t)tfirst * NT + j] * F_L2E;
    for (int s = 0; s < SCH; s++) {
      int t = t0 + SCH - 1 - s;
      float fe_n = feats[(size_t)t * NT + j] * F_L2E;
      float out;
      if (t == LSEQ - 1) {
        out = b;
      } else {
        if (a) U[j] = b + fe;
        barrier_lds();
        float um = a ? U[j] : -3e38f;
        for (int off = 32; off; off >>= 1) um = fmaxf(um, __shfl_xor(um, off));
        float m = rm + um;
        float ss = 0.f;
#pragma unroll
        for (int k = 0; k < NT; k++) ss += ex2(trr[k] + U[k] - m);
        out = m + lg2(ss);
        barrier_lds();
      }
      if (a) wsB[(size_t)t * NT + j] = out * F_LN2;
      b = out;
      fe = fe_n;
    }
  }
}

// ---------------------------------------------------------------------------
__global__ void k_finish(const float* __restrict__ wsA, const float* __restrict__ wsB,
                         float* __restrict__ out){
  int t = blockIdx.x * 256 + threadIdx.x;
  float m = -3e38f; int bi = 0;
  for (int i = 0; i < NT; i++) {
    float sc = wsA[(size_t)t * NT + i] + wsB[(size_t)t * NT + i];
    out[(size_t)t * NT + i] = sc;
    if (sc > m) { m = sc; bi = i; }
  }
  out[(size_t)LSEQ * NT + t] = (float)bi;
}

// ---------------------------------------------------------------------------
extern "C" void kernel_launch(void* const* d_in, const int* in_sizes, int n_in,
                              void* d_out, int out_size, void* d_ws, size_t ws_size,
                              hipStream_t stream) {
  const int*   words  = (const int*)  d_in[0];
  const float* embed  = (const float*)d_in[1];
  const float* Wih_f  = (const float*)d_in[2];
  const float* Whh_f  = (const float*)d_in[3];
  const float* b_f    = (const float*)d_in[4];
  const float* Wih_b  = (const float*)d_in[5];
  const float* Whh_b  = (const float*)d_in[6];
  const float* b_b    = (const float*)d_in[7];
  const float* W_out  = (const float*)d_in[8];
  const float* b_out  = (const float*)d_in[9];
  const float* trans  = (const float*)d_in[10];
  float* out = (float*)d_out;

  float* wsf = (float*)d_ws;
  size_t off = 0;
  float* G_f   = wsf + off; off += (size_t)LSEQ * 1024;
  float* G_b   = wsf + off; off += (size_t)LSEQ * 1024;
  float* hf    = wsf + off; off += (size_t)LSEQ * 256;
  float* hb    = wsf + off; off += (size_t)LSEQ * 256;
  float* feats = wsf + off; off += (size_t)LSEQ * NT + 16;
  float* wsA   = wsf + off; off += (size_t)LSEQ * NT + 16;
  float* wsB   = wsf + off; off += (size_t)LSEQ * NT + 16;
  float* facP  = wsf + off; off += 2048;
  int*   Wq    = (int*)(wsf + off); off += 2 * 1024 * 64;
  // CRF scan scratch overlaps G_f (dead after k_lstm6)
  float* Pg    = G_f;
  float* rmaxG = G_f + 256 * (NT * NP);
  float* vIn   = rmaxG + 256 * NT + 32;

  k_quant<<<2048, 64, 0, stream>>>(Whh_f, Whh_b, Wq, facP);
  k_gproj<<<dim3(512, 2), 256, 0, stream>>>(words, embed, Wih_f, b_f, Wih_b, b_b, G_f, G_b);
  k_lstm6<<<2, 512, 0, stream>>>(Wq, facP, G_f, G_b, hf, hb);
  k_feats<<<512, 256, 0, stream>>>(hf, hb, W_out, b_out, feats);
  k_crf_p1<<<256, 320, 0, stream>>>(feats, trans, Pg, rmaxG);
  k_crf_p2<<<2, 64, 0, stream>>>(trans, Pg, rmaxG, vIn);
  k_crf_p3<<<256, 64, 0, stream>>>(feats, trans, vIn, wsA, wsB);
  k_finish<<<32, 256, 0, stream>>>(wsA, wsB, out);
}